// Round 4
// baseline (2027.156 us; speedup 1.0000x reference)
//
#include <hip/hip_runtime.h>

// GraphSAGE 2-layer + linear head, N=200000 nodes, E=6.4M edges.
//
// Decomposition: out = mean2 @ (W2l@Wlin) + h1 @ (W2r@Wlin) + (b2@Wlin + blin)
//   A = W2l@Wlin (32x2), B = W2r@Wlin (32x2), c = b2@Wlin + blin (2)
//   g1 = h1@A, hB = h1@B  -> layer-2 edge pass scatters only 2 floats/edge.
//
// ws layout (floats): agg1[4N] (x0,x1,x2,count) | agg2[2N] | g1[2N] | hB[2N] | ABc[130]

__global__ void precomp_kernel(const float* __restrict__ W2l, const float* __restrict__ W2r,
                               const float* __restrict__ b2, const float* __restrict__ Wlin,
                               const float* __restrict__ blin, float* __restrict__ ABc) {
    int t = threadIdx.x;
    if (t < 64) {
        int r = t >> 1, c = t & 1;
        float sA = 0.f, sB = 0.f;
        for (int k = 0; k < 16; ++k) {
            float w = Wlin[k * 2 + c];
            sA += W2l[r * 16 + k] * w;   // W2l is (32,16) row-major
            sB += W2r[r * 16 + k] * w;
        }
        ABc[t] = sA;
        ABc[64 + t] = sB;
    } else if (t < 66) {
        int c = t - 64;
        float s = blin[c];
        for (int k = 0; k < 16; ++k) s += b2[k] * Wlin[k * 2 + c];
        ABc[128 + c] = s;
    }
}

// Layer-1 aggregation: agg1[dst] += (x[src], 1.0)
__global__ void edge1_kernel(const int* __restrict__ src, const int* __restrict__ dst,
                             const float* __restrict__ x, float* __restrict__ agg1, int E) {
    int stride = gridDim.x * blockDim.x;
    for (int e = blockIdx.x * blockDim.x + threadIdx.x; e < E; e += stride) {
        int s = src[e], d = dst[e];
        float x0 = x[3 * s], x1 = x[3 * s + 1], x2 = x[3 * s + 2];
        float* p = agg1 + 4 * (size_t)d;
        atomicAdd(p + 0, x0);
        atomicAdd(p + 1, x1);
        atomicAdd(p + 2, x2);
        atomicAdd(p + 3, 1.0f);
    }
}

// Per-node: mean1 -> h1 = relu(mean1@W1l + x@W1r + b1) in regs -> g1=h1@A, hB=h1@B
__global__ void node1_kernel(const float* __restrict__ agg1, const float* __restrict__ x,
                             const float* __restrict__ W1l, const float* __restrict__ W1r,
                             const float* __restrict__ b1, const float* __restrict__ ABc,
                             float* __restrict__ g1, float* __restrict__ hB, int N) {
    __shared__ float sW1l[96], sW1r[96], sb1[32], sA[64], sB[64];
    int tid = threadIdx.x, bs = blockDim.x;
    for (int i = tid; i < 96; i += bs) { sW1l[i] = W1l[i]; sW1r[i] = W1r[i]; }
    for (int i = tid; i < 32; i += bs) sb1[i] = b1[i];
    for (int i = tid; i < 64; i += bs) { sA[i] = ABc[i]; sB[i] = ABc[64 + i]; }
    __syncthreads();
    int stride = gridDim.x * bs;
    for (int n = blockIdx.x * bs + tid; n < N; n += stride) {
        float4 a = *(const float4*)(agg1 + 4 * (size_t)n);   // 16B aligned
        float inv = 1.0f / fmaxf(a.w, 1.0f);
        float m0 = a.x * inv, m1 = a.y * inv, m2 = a.z * inv;
        float x0 = x[3 * n], x1 = x[3 * n + 1], x2 = x[3 * n + 2];
        float gA0 = 0.f, gA1 = 0.f, gB0 = 0.f, gB1 = 0.f;
#pragma unroll
        for (int k = 0; k < 32; ++k) {
            float h = m0 * sW1l[k] + m1 * sW1l[32 + k] + m2 * sW1l[64 + k]
                    + x0 * sW1r[k] + x1 * sW1r[32 + k] + x2 * sW1r[64 + k] + sb1[k];
            h = fmaxf(h, 0.0f);
            gA0 += h * sA[2 * k];     gA1 += h * sA[2 * k + 1];
            gB0 += h * sB[2 * k];     gB1 += h * sB[2 * k + 1];
        }
        *(float2*)(g1 + 2 * (size_t)n) = make_float2(gA0, gA1);
        *(float2*)(hB + 2 * (size_t)n) = make_float2(gB0, gB1);
    }
}

// Layer-2 aggregation (folded): agg2[dst] += g1[src]  (2 floats/edge)
__global__ void edge2_kernel(const int* __restrict__ src, const int* __restrict__ dst,
                             const float* __restrict__ g1, float* __restrict__ agg2, int E) {
    int stride = gridDim.x * blockDim.x;
    for (int e = blockIdx.x * blockDim.x + threadIdx.x; e < E; e += stride) {
        int s = src[e], d = dst[e];
        float2 g = *(const float2*)(g1 + 2 * (size_t)s);
        atomicAdd(agg2 + 2 * (size_t)d + 0, g.x);
        atomicAdd(agg2 + 2 * (size_t)d + 1, g.y);
    }
}

// out = agg2/cnt + hB + c
__global__ void node2_kernel(const float* __restrict__ agg1, const float* __restrict__ agg2,
                             const float* __restrict__ hB, const float* __restrict__ ABc,
                             float* __restrict__ out, int N) {
    float c0 = ABc[128], c1 = ABc[129];
    int stride = gridDim.x * blockDim.x;
    for (int n = blockIdx.x * blockDim.x + threadIdx.x; n < N; n += stride) {
        float cw = agg1[4 * (size_t)n + 3];
        float inv = 1.0f / fmaxf(cw, 1.0f);
        float2 a = *(const float2*)(agg2 + 2 * (size_t)n);
        float2 b = *(const float2*)(hB + 2 * (size_t)n);
        *(float2*)(out + 2 * (size_t)n) = make_float2(a.x * inv + b.x + c0,
                                                      a.y * inv + b.y + c1);
    }
}

extern "C" void kernel_launch(void* const* d_in, const int* in_sizes, int n_in,
                              void* d_out, int out_size, void* d_ws, size_t ws_size,
                              hipStream_t stream) {
    const float* x    = (const float*)d_in[0];
    const int*   ei   = (const int*)d_in[1];   // [2, E] flat: src = ei[0:E], dst = ei[E:2E]
    const float* W1l  = (const float*)d_in[2];
    const float* W1r  = (const float*)d_in[3];
    const float* b1   = (const float*)d_in[4];
    const float* W2l  = (const float*)d_in[5];
    const float* W2r  = (const float*)d_in[6];
    const float* b2   = (const float*)d_in[7];
    const float* Wlin = (const float*)d_in[8];
    const float* blin = (const float*)d_in[9];
    float* out = (float*)d_out;

    const int N = in_sizes[0] / 3;
    const int E = in_sizes[1] / 2;

    float* ws   = (float*)d_ws;
    float* agg1 = ws;                    // 4N
    float* agg2 = ws + (size_t)4 * N;    // 2N
    float* g1   = ws + (size_t)6 * N;    // 2N
    float* hB   = ws + (size_t)8 * N;    // 2N
    float* ABc  = ws + (size_t)10 * N;   // 130

    // zero agg1 + agg2 (contiguous first 6N floats)
    hipMemsetAsync(agg1, 0, (size_t)6 * N * sizeof(float), stream);

    precomp_kernel<<<1, 128, 0, stream>>>(W2l, W2r, b2, Wlin, blin, ABc);

    int eblocks = (E + 255) / 256;
    if (eblocks > 6144) eblocks = 6144;          // grid-stride
    int nblocks = (N + 255) / 256;

    edge1_kernel<<<eblocks, 256, 0, stream>>>(ei, ei + E, x, agg1, E);
    node1_kernel<<<nblocks, 256, 0, stream>>>(agg1, x, W1l, W1r, b1, ABc, g1, hB, N);
    edge2_kernel<<<eblocks, 256, 0, stream>>>(ei, ei + E, g1, agg2, E);
    node2_kernel<<<nblocks, 256, 0, stream>>>(agg1, agg2, hB, ABc, out, N);
}

// Round 5
// 989.158 us; speedup vs baseline: 2.0494x; 2.0494x over previous
//
#include <hip/hip_runtime.h>

// GraphSAGE 2-layer + linear head, N=200000, E=6.4M.
//
// out = mean2 @ (W2l@Wlin) + h1 @ (W2r@Wlin) + (b2@Wlin + blin)
//   A = W2l@Wlin (32x2), B = W2r@Wlin (32x2), c = b2@Wlin + blin (2)
//
// Round-4 strategy: device-scope f32 atomics cost ~32B memory-side RMW each
// (measured: 800MB WRITE_SIZE for 25.6M atomics, ~20G atomics/s). Build a CSR
// (2 int atomics/edge) once, then aggregate both layers with atomic-free
// gathers (x and g1 are L2-resident).
//
// CSR ws layout (4B words):
//   [0..1]                 gcursor (+pad)
//   [2       .. 2+N)       cnt      (histogram / degrees)
//   [2+N     .. 2+2N)      offsets
//   [2+2N    .. 2+3N)      cursor
//   [2+3N    .. 2+3N+E)    adj
//   [g1off   .. +2N)       g1   (float2 per node)   g1off = 2+3N+E (even)
//   [hBoff   .. +2N)       hB
//   [abcoff  .. +130)      ABc
// Fallback (ws too small): round-3 atomic-scatter path.

// ---------- shared: fold layer-2 + head ----------
__global__ void precomp_kernel(const float* __restrict__ W2l, const float* __restrict__ W2r,
                               const float* __restrict__ b2, const float* __restrict__ Wlin,
                               const float* __restrict__ blin, float* __restrict__ ABc) {
    int t = threadIdx.x;
    if (t < 64) {
        int r = t >> 1, c = t & 1;
        float sA = 0.f, sB = 0.f;
        for (int k = 0; k < 16; ++k) {
            float w = Wlin[k * 2 + c];
            sA += W2l[r * 16 + k] * w;   // W2l is (32,16) row-major
            sB += W2r[r * 16 + k] * w;
        }
        ABc[t] = sA;
        ABc[64 + t] = sB;
    } else if (t < 66) {
        int c = t - 64;
        float s = blin[c];
        for (int k = 0; k < 16; ++k) s += b2[k] * Wlin[k * 2 + c];
        ABc[128 + c] = s;
    }
}

// ---------- CSR build ----------
__global__ void hist_kernel(const int* __restrict__ dst, int* __restrict__ cnt, int E) {
    int stride = gridDim.x * blockDim.x;
    for (int e = blockIdx.x * blockDim.x + threadIdx.x; e < E; e += stride)
        atomicAdd(cnt + dst[e], 1);
}

__global__ void alloc_kernel(const int* __restrict__ cnt, int* __restrict__ offsets,
                             int* __restrict__ cursor, int* __restrict__ gcursor, int N) {
    __shared__ int s[256];
    __shared__ int sbase;
    int tid = threadIdx.x;
    int n = blockIdx.x * 256 + tid;
    int v = (n < N) ? cnt[n] : 0;
    s[tid] = v;
    __syncthreads();
    // Hillis-Steele inclusive scan
    for (int d = 1; d < 256; d <<= 1) {
        int t = (tid >= d) ? s[tid - d] : 0;
        __syncthreads();
        s[tid] += t;
        __syncthreads();
    }
    if (tid == 255) sbase = atomicAdd(gcursor, s[255]);
    __syncthreads();
    if (n < N) {
        int off = sbase + s[tid] - v;   // exclusive within block + block base
        offsets[n] = off;
        cursor[n] = off;
    }
}

__global__ void place_kernel(const int* __restrict__ src, const int* __restrict__ dst,
                             int* __restrict__ cursor, int* __restrict__ adj, int E) {
    int stride = gridDim.x * blockDim.x;
    for (int e = blockIdx.x * blockDim.x + threadIdx.x; e < E; e += stride) {
        int pos = atomicAdd(cursor + dst[e], 1);
        adj[pos] = src[e];
    }
}

// ---------- fused gather + node compute, layer 1 ----------
__global__ void node1g_kernel(const int* __restrict__ cnt, const int* __restrict__ offsets,
                              const int* __restrict__ adj, const float* __restrict__ x,
                              const float* __restrict__ W1l, const float* __restrict__ W1r,
                              const float* __restrict__ b1, const float* __restrict__ ABc,
                              float* __restrict__ g1, float* __restrict__ hB, int N) {
    __shared__ float sW1l[96], sW1r[96], sb1[32], sA[64], sB[64];
    int tid = threadIdx.x, bs = blockDim.x;
    for (int i = tid; i < 96; i += bs) { sW1l[i] = W1l[i]; sW1r[i] = W1r[i]; }
    for (int i = tid; i < 32; i += bs) sb1[i] = b1[i];
    for (int i = tid; i < 64; i += bs) { sA[i] = ABc[i]; sB[i] = ABc[64 + i]; }
    __syncthreads();
    int stride = gridDim.x * bs;
    for (int n = blockIdx.x * bs + tid; n < N; n += stride) {
        int deg = cnt[n];
        int off = offsets[n];
        float sx0 = 0.f, sx1 = 0.f, sx2 = 0.f;
        for (int j = 0; j < deg; ++j) {
            int s = adj[off + j];
            sx0 += x[3 * (size_t)s];
            sx1 += x[3 * (size_t)s + 1];
            sx2 += x[3 * (size_t)s + 2];
        }
        float inv = 1.0f / fmaxf((float)deg, 1.0f);
        float m0 = sx0 * inv, m1 = sx1 * inv, m2 = sx2 * inv;
        float x0 = x[3 * (size_t)n], x1 = x[3 * (size_t)n + 1], x2 = x[3 * (size_t)n + 2];
        float gA0 = 0.f, gA1 = 0.f, gB0 = 0.f, gB1 = 0.f;
#pragma unroll
        for (int k = 0; k < 32; ++k) {
            float h = m0 * sW1l[k] + m1 * sW1l[32 + k] + m2 * sW1l[64 + k]
                    + x0 * sW1r[k] + x1 * sW1r[32 + k] + x2 * sW1r[64 + k] + sb1[k];
            h = fmaxf(h, 0.0f);
            gA0 += h * sA[2 * k];     gA1 += h * sA[2 * k + 1];
            gB0 += h * sB[2 * k];     gB1 += h * sB[2 * k + 1];
        }
        *(float2*)(g1 + 2 * (size_t)n) = make_float2(gA0, gA1);
        *(float2*)(hB + 2 * (size_t)n) = make_float2(gB0, gB1);
    }
}

// ---------- fused gather + output, layer 2 ----------
__global__ void node2g_kernel(const int* __restrict__ cnt, const int* __restrict__ offsets,
                              const int* __restrict__ adj, const float* __restrict__ g1,
                              const float* __restrict__ hB, const float* __restrict__ ABc,
                              float* __restrict__ out, int N) {
    float c0 = ABc[128], c1 = ABc[129];
    int stride = gridDim.x * blockDim.x;
    for (int n = blockIdx.x * blockDim.x + threadIdx.x; n < N; n += stride) {
        int deg = cnt[n];
        int off = offsets[n];
        float s0 = 0.f, s1 = 0.f;
        for (int j = 0; j < deg; ++j) {
            int s = adj[off + j];
            float2 g = *(const float2*)(g1 + 2 * (size_t)s);
            s0 += g.x; s1 += g.y;
        }
        float inv = 1.0f / fmaxf((float)deg, 1.0f);
        float2 b = *(const float2*)(hB + 2 * (size_t)n);
        *(float2*)(out + 2 * (size_t)n) = make_float2(s0 * inv + b.x + c0,
                                                      s1 * inv + b.y + c1);
    }
}

// ---------- fallback path (round-3, atomic scatter) ----------
__global__ void edge1_kernel(const int* __restrict__ src, const int* __restrict__ dst,
                             const float* __restrict__ x, float* __restrict__ agg1, int E) {
    int stride = gridDim.x * blockDim.x;
    for (int e = blockIdx.x * blockDim.x + threadIdx.x; e < E; e += stride) {
        int s = src[e], d = dst[e];
        float* p = agg1 + 4 * (size_t)d;
        atomicAdd(p + 0, x[3 * s]);
        atomicAdd(p + 1, x[3 * s + 1]);
        atomicAdd(p + 2, x[3 * s + 2]);
        atomicAdd(p + 3, 1.0f);
    }
}

__global__ void node1_kernel(const float* __restrict__ agg1, const float* __restrict__ x,
                             const float* __restrict__ W1l, const float* __restrict__ W1r,
                             const float* __restrict__ b1, const float* __restrict__ ABc,
                             float* __restrict__ g1, float* __restrict__ hB, int N) {
    __shared__ float sW1l[96], sW1r[96], sb1[32], sA[64], sB[64];
    int tid = threadIdx.x, bs = blockDim.x;
    for (int i = tid; i < 96; i += bs) { sW1l[i] = W1l[i]; sW1r[i] = W1r[i]; }
    for (int i = tid; i < 32; i += bs) sb1[i] = b1[i];
    for (int i = tid; i < 64; i += bs) { sA[i] = ABc[i]; sB[i] = ABc[64 + i]; }
    __syncthreads();
    int stride = gridDim.x * bs;
    for (int n = blockIdx.x * bs + tid; n < N; n += stride) {
        float4 a = *(const float4*)(agg1 + 4 * (size_t)n);
        float inv = 1.0f / fmaxf(a.w, 1.0f);
        float m0 = a.x * inv, m1 = a.y * inv, m2 = a.z * inv;
        float x0 = x[3 * n], x1 = x[3 * n + 1], x2 = x[3 * n + 2];
        float gA0 = 0.f, gA1 = 0.f, gB0 = 0.f, gB1 = 0.f;
#pragma unroll
        for (int k = 0; k < 32; ++k) {
            float h = m0 * sW1l[k] + m1 * sW1l[32 + k] + m2 * sW1l[64 + k]
                    + x0 * sW1r[k] + x1 * sW1r[32 + k] + x2 * sW1r[64 + k] + sb1[k];
            h = fmaxf(h, 0.0f);
            gA0 += h * sA[2 * k];     gA1 += h * sA[2 * k + 1];
            gB0 += h * sB[2 * k];     gB1 += h * sB[2 * k + 1];
        }
        *(float2*)(g1 + 2 * (size_t)n) = make_float2(gA0, gA1);
        *(float2*)(hB + 2 * (size_t)n) = make_float2(gB0, gB1);
    }
}

__global__ void edge2_kernel(const int* __restrict__ src, const int* __restrict__ dst,
                             const float* __restrict__ g1, float* __restrict__ agg2, int E) {
    int stride = gridDim.x * blockDim.x;
    for (int e = blockIdx.x * blockDim.x + threadIdx.x; e < E; e += stride) {
        int s = src[e], d = dst[e];
        float2 g = *(const float2*)(g1 + 2 * (size_t)s);
        atomicAdd(agg2 + 2 * (size_t)d + 0, g.x);
        atomicAdd(agg2 + 2 * (size_t)d + 1, g.y);
    }
}

__global__ void node2_kernel(const float* __restrict__ agg1, const float* __restrict__ agg2,
                             const float* __restrict__ hB, const float* __restrict__ ABc,
                             float* __restrict__ out, int N) {
    float c0 = ABc[128], c1 = ABc[129];
    int stride = gridDim.x * blockDim.x;
    for (int n = blockIdx.x * blockDim.x + threadIdx.x; n < N; n += stride) {
        float inv = 1.0f / fmaxf(agg1[4 * (size_t)n + 3], 1.0f);
        float2 a = *(const float2*)(agg2 + 2 * (size_t)n);
        float2 b = *(const float2*)(hB + 2 * (size_t)n);
        *(float2*)(out + 2 * (size_t)n) = make_float2(a.x * inv + b.x + c0,
                                                      a.y * inv + b.y + c1);
    }
}

extern "C" void kernel_launch(void* const* d_in, const int* in_sizes, int n_in,
                              void* d_out, int out_size, void* d_ws, size_t ws_size,
                              hipStream_t stream) {
    const float* x    = (const float*)d_in[0];
    const int*   ei   = (const int*)d_in[1];   // [2,E] flat: src = ei[0:E], dst = ei[E:2E]
    const float* W1l  = (const float*)d_in[2];
    const float* W1r  = (const float*)d_in[3];
    const float* b1   = (const float*)d_in[4];
    const float* W2l  = (const float*)d_in[5];
    const float* W2r  = (const float*)d_in[6];
    const float* b2   = (const float*)d_in[7];
    const float* Wlin = (const float*)d_in[8];
    const float* blin = (const float*)d_in[9];
    float* out = (float*)d_out;

    const int N = in_sizes[0] / 3;
    const int E = in_sizes[1] / 2;
    const int* src = ei;
    const int* dst = ei + E;

    int eblocks = (E + 255) / 256;
    if (eblocks > 6144) eblocks = 6144;
    int nblocks = (N + 255) / 256;

    size_t csr_words = (size_t)2 + 3 * (size_t)N + (size_t)E + 4 * (size_t)N + 130;
    if (ws_size >= csr_words * 4) {
        // ---- CSR path ----
        int*   iws     = (int*)d_ws;
        int*   gcursor = iws;                                   // [0..1] (pad keeps 8B parity)
        int*   cnt     = iws + 2;                               // N
        int*   offsets = iws + 2 + (size_t)N;                   // N
        int*   cursor  = iws + 2 + 2 * (size_t)N;               // N
        int*   adj     = iws + 2 + 3 * (size_t)N;               // E
        float* g1      = (float*)(iws + 2 + 3 * (size_t)N + (size_t)E);  // 2N (8B-aligned)
        float* hB      = g1 + 2 * (size_t)N;                    // 2N
        float* ABc     = hB + 2 * (size_t)N;                    // 130

        hipMemsetAsync(iws, 0, ((size_t)N + 2) * sizeof(int), stream);  // gcursor + cnt
        precomp_kernel<<<1, 128, 0, stream>>>(W2l, W2r, b2, Wlin, blin, ABc);

        hist_kernel <<<eblocks, 256, 0, stream>>>(dst, cnt, E);
        alloc_kernel<<<nblocks, 256, 0, stream>>>(cnt, offsets, cursor, gcursor, N);
        place_kernel<<<eblocks, 256, 0, stream>>>(src, dst, cursor, adj, E);

        node1g_kernel<<<nblocks, 256, 0, stream>>>(cnt, offsets, adj, x,
                                                   W1l, W1r, b1, ABc, g1, hB, N);
        node2g_kernel<<<nblocks, 256, 0, stream>>>(cnt, offsets, adj, g1, hB, ABc, out, N);
    } else {
        // ---- fallback: round-3 atomic-scatter path ----
        float* ws   = (float*)d_ws;
        float* agg1 = ws;                    // 4N (x0,x1,x2,count)
        float* agg2 = ws + (size_t)4 * N;    // 2N
        float* g1   = ws + (size_t)6 * N;    // 2N
        float* hB   = ws + (size_t)8 * N;    // 2N
        float* ABc  = ws + (size_t)10 * N;   // 130

        hipMemsetAsync(agg1, 0, (size_t)6 * N * sizeof(float), stream);
        precomp_kernel<<<1, 128, 0, stream>>>(W2l, W2r, b2, Wlin, blin, ABc);
        edge1_kernel<<<eblocks, 256, 0, stream>>>(src, dst, x, agg1, E);
        node1_kernel<<<nblocks, 256, 0, stream>>>(agg1, x, W1l, W1r, b1, ABc, g1, hB, N);
        edge2_kernel<<<eblocks, 256, 0, stream>>>(src, dst, g1, agg2, E);
        node2_kernel<<<nblocks, 256, 0, stream>>>(agg1, agg2, hB, ABc, out, N);
    }
}

// Round 6
// 941.973 us; speedup vs baseline: 2.1520x; 1.0501x over previous
//
#include <hip/hip_runtime.h>

// GraphSAGE 2-layer + linear head, N=200000, E=6.4M.
//
// out = mean2 @ (W2l@Wlin) + h1 @ (W2r@Wlin) + (b2@Wlin + blin)
//   A = W2l@Wlin (32x2), B = W2r@Wlin (32x2), c = b2@Wlin + blin (2)
//
// Round-5: global atomics are the bottleneck (place_kernel: 6.4M returning
// atomics = 575us @ ~11G/s). Replace CSR entirely with node-tiled LDS
// aggregation: blocks own (node-tile, edge-chunk), stream dst (L2/L3-resident,
// chunk pinned per-XCD via blockIdx&7), LDS-atomic-accumulate matches, flush
// as plain coalesced stores to per-chunk partials; node pass sums 8 partials.
// Zero global atomics.
//
// ws layout (floats):
//   [0 .. 8*N*4)        partials1 (chunk-major, float4/node)   25.6MB
//   [0 .. 8*N*2)        partials2 (reuses partials1 region)    12.8MB
//   [P1 .. +2N)         g1
//   [.. +2N)            hB
//   [.. +N)             inv
//   [.. +130)           ABc
// Fallback (ws too small): round-3 atomic-scatter path.

#define NCHUNK 8
#define TILE1 4096
#define TILE2 8192

// ---------- fold layer-2 + head ----------
__global__ void precomp_kernel(const float* __restrict__ W2l, const float* __restrict__ W2r,
                               const float* __restrict__ b2, const float* __restrict__ Wlin,
                               const float* __restrict__ blin, float* __restrict__ ABc) {
    int t = threadIdx.x;
    if (t < 64) {
        int r = t >> 1, c = t & 1;
        float sA = 0.f, sB = 0.f;
        for (int k = 0; k < 16; ++k) {
            float w = Wlin[k * 2 + c];
            sA += W2l[r * 16 + k] * w;   // W2l is (32,16) row-major
            sB += W2r[r * 16 + k] * w;
        }
        ABc[t] = sA;
        ABc[64 + t] = sB;
    } else if (t < 66) {
        int c = t - 64;
        float s = blin[c];
        for (int k = 0; k < 16; ++k) s += b2[k] * Wlin[k * 2 + c];
        ABc[128 + c] = s;
    }
}

// ---------- layer-1 tiled scatter: acc[dst-base] += (x[src],1) in LDS ----------
__global__ __launch_bounds__(512) void tile1_kernel(const int* __restrict__ src,
        const int* __restrict__ dst, const float* __restrict__ x,
        float* __restrict__ partials1, int N, int E, int EC) {
    __shared__ float acc[TILE1 * 4];   // 64KB
    const int tid = threadIdx.x;
    const int chunk = blockIdx.x & (NCHUNK - 1);   // == XCD id under default round-robin
    const int base = (blockIdx.x >> 3) * TILE1;
    for (int i = tid; i < TILE1 * 4; i += 512) acc[i] = 0.f;
    __syncthreads();

    int e0 = chunk * EC;
    if (e0 > E) e0 = E;
    int e1 = e0 + EC; if (e1 > E) e1 = E;
    int nv = (e1 - e0) >> 2;                    // int4 groups (EC is 16B-aligned mult of 4)
    const int4* d4p = (const int4*)(dst + e0);

#define DO_E1(dd, ee) { unsigned r = (unsigned)(dd) - (unsigned)base;            \
    if (r < (unsigned)TILE1) { int s = src[ee];                                  \
        const float* xp = x + 3 * (size_t)s;                                     \
        atomicAdd(&acc[r * 4 + 0], xp[0]); atomicAdd(&acc[r * 4 + 1], xp[1]);    \
        atomicAdd(&acc[r * 4 + 2], xp[2]); atomicAdd(&acc[r * 4 + 3], 1.0f); } }

    for (int i = tid; i < nv; i += 512) {
        int4 d4 = d4p[i];
        int eb = e0 + (i << 2);
        DO_E1(d4.x, eb);     DO_E1(d4.y, eb + 1);
        DO_E1(d4.z, eb + 2); DO_E1(d4.w, eb + 3);
    }
    for (int e = e0 + (nv << 2) + tid; e < e1; e += 512) DO_E1(dst[e], e);
#undef DO_E1

    __syncthreads();
    float* p = partials1 + ((size_t)chunk * N + base) * 4;
    int lim = N - base; if (lim > TILE1) lim = TILE1;
    for (int i = tid; i < lim; i += 512)
        *(float4*)(p + (size_t)i * 4) = *(const float4*)(acc + i * 4);
}

// ---------- node pass 1: sum partials -> mean1 -> h1 (regs) -> g1,hB; store inv ----------
__global__ void node1t_kernel(const float* __restrict__ partials1, const float* __restrict__ x,
                              const float* __restrict__ W1l, const float* __restrict__ W1r,
                              const float* __restrict__ b1, const float* __restrict__ ABc,
                              float* __restrict__ g1, float* __restrict__ hB,
                              float* __restrict__ invArr, int N) {
    __shared__ float sW1l[96], sW1r[96], sb1[32], sA[64], sB[64];
    int tid = threadIdx.x;
    for (int i = tid; i < 96; i += 256) { sW1l[i] = W1l[i]; sW1r[i] = W1r[i]; }
    for (int i = tid; i < 32; i += 256) sb1[i] = b1[i];
    for (int i = tid; i < 64; i += 256) { sA[i] = ABc[i]; sB[i] = ABc[64 + i]; }
    __syncthreads();
    int n = blockIdx.x * 256 + tid;
    if (n >= N) return;
    float sx = 0.f, sy = 0.f, sz = 0.f, cw = 0.f;
#pragma unroll
    for (int c = 0; c < NCHUNK; ++c) {
        float4 v = *(const float4*)(partials1 + ((size_t)c * N + n) * 4);
        sx += v.x; sy += v.y; sz += v.z; cw += v.w;
    }
    float inv = 1.0f / fmaxf(cw, 1.0f);
    float m0 = sx * inv, m1 = sy * inv, m2 = sz * inv;
    float x0 = x[3 * (size_t)n], x1 = x[3 * (size_t)n + 1], x2 = x[3 * (size_t)n + 2];
    float gA0 = 0.f, gA1 = 0.f, gB0 = 0.f, gB1 = 0.f;
#pragma unroll
    for (int k = 0; k < 32; ++k) {
        float h = m0 * sW1l[k] + m1 * sW1l[32 + k] + m2 * sW1l[64 + k]
                + x0 * sW1r[k] + x1 * sW1r[32 + k] + x2 * sW1r[64 + k] + sb1[k];
        h = fmaxf(h, 0.0f);
        gA0 += h * sA[2 * k];     gA1 += h * sA[2 * k + 1];
        gB0 += h * sB[2 * k];     gB1 += h * sB[2 * k + 1];
    }
    *(float2*)(g1 + 2 * (size_t)n) = make_float2(gA0, gA1);
    *(float2*)(hB + 2 * (size_t)n) = make_float2(gB0, gB1);
    invArr[n] = inv;
}

// ---------- layer-2 tiled scatter: acc[dst-base] += g1[src] in LDS ----------
__global__ __launch_bounds__(512) void tile2_kernel(const int* __restrict__ src,
        const int* __restrict__ dst, const float* __restrict__ g1,
        float* __restrict__ partials2, int N, int E, int EC) {
    __shared__ float acc[TILE2 * 2];   // 64KB
    const int tid = threadIdx.x;
    const int chunk = blockIdx.x & (NCHUNK - 1);
    const int base = (blockIdx.x >> 3) * TILE2;
    for (int i = tid; i < TILE2 * 2; i += 512) acc[i] = 0.f;
    __syncthreads();

    int e0 = chunk * EC;
    if (e0 > E) e0 = E;
    int e1 = e0 + EC; if (e1 > E) e1 = E;
    int nv = (e1 - e0) >> 2;
    const int4* d4p = (const int4*)(dst + e0);

#define DO_E2(dd, ee) { unsigned r = (unsigned)(dd) - (unsigned)base;            \
    if (r < (unsigned)TILE2) { int s = src[ee];                                  \
        float2 g = *(const float2*)(g1 + 2 * (size_t)s);                         \
        atomicAdd(&acc[r * 2 + 0], g.x); atomicAdd(&acc[r * 2 + 1], g.y); } }

    for (int i = tid; i < nv; i += 512) {
        int4 d4 = d4p[i];
        int eb = e0 + (i << 2);
        DO_E2(d4.x, eb);     DO_E2(d4.y, eb + 1);
        DO_E2(d4.z, eb + 2); DO_E2(d4.w, eb + 3);
    }
    for (int e = e0 + (nv << 2) + tid; e < e1; e += 512) DO_E2(dst[e], e);
#undef DO_E2

    __syncthreads();
    float* p = partials2 + ((size_t)chunk * N + base) * 2;
    int lim = N - base; if (lim > TILE2) lim = TILE2;
    for (int i = tid; i < lim; i += 512)
        *(float2*)(p + (size_t)i * 2) = *(const float2*)(acc + i * 2);
}

// ---------- node pass 2: out = (sum partials2)*inv + hB + c ----------
__global__ void node2t_kernel(const float* __restrict__ partials2, const float* __restrict__ invArr,
                              const float* __restrict__ hB, const float* __restrict__ ABc,
                              float* __restrict__ out, int N) {
    int n = blockIdx.x * 256 + threadIdx.x;
    if (n >= N) return;
    float c0 = ABc[128], c1 = ABc[129];
    float s0 = 0.f, s1 = 0.f;
#pragma unroll
    for (int c = 0; c < NCHUNK; ++c) {
        float2 v = *(const float2*)(partials2 + ((size_t)c * N + n) * 2);
        s0 += v.x; s1 += v.y;
    }
    float inv = invArr[n];
    float2 b = *(const float2*)(hB + 2 * (size_t)n);
    *(float2*)(out + 2 * (size_t)n) = make_float2(s0 * inv + b.x + c0,
                                                  s1 * inv + b.y + c1);
}

// ---------- fallback path (round-3, atomic scatter; proven) ----------
__global__ void edge1_kernel(const int* __restrict__ src, const int* __restrict__ dst,
                             const float* __restrict__ x, float* __restrict__ agg1, int E) {
    int stride = gridDim.x * blockDim.x;
    for (int e = blockIdx.x * blockDim.x + threadIdx.x; e < E; e += stride) {
        int s = src[e], d = dst[e];
        float* p = agg1 + 4 * (size_t)d;
        atomicAdd(p + 0, x[3 * s]);
        atomicAdd(p + 1, x[3 * s + 1]);
        atomicAdd(p + 2, x[3 * s + 2]);
        atomicAdd(p + 3, 1.0f);
    }
}

__global__ void node1f_kernel(const float* __restrict__ agg1, const float* __restrict__ x,
                              const float* __restrict__ W1l, const float* __restrict__ W1r,
                              const float* __restrict__ b1, const float* __restrict__ ABc,
                              float* __restrict__ g1, float* __restrict__ hB, int N) {
    __shared__ float sW1l[96], sW1r[96], sb1[32], sA[64], sB[64];
    int tid = threadIdx.x, bs = blockDim.x;
    for (int i = tid; i < 96; i += bs) { sW1l[i] = W1l[i]; sW1r[i] = W1r[i]; }
    for (int i = tid; i < 32; i += bs) sb1[i] = b1[i];
    for (int i = tid; i < 64; i += bs) { sA[i] = ABc[i]; sB[i] = ABc[64 + i]; }
    __syncthreads();
    int stride = gridDim.x * bs;
    for (int n = blockIdx.x * bs + tid; n < N; n += stride) {
        float4 a = *(const float4*)(agg1 + 4 * (size_t)n);
        float inv = 1.0f / fmaxf(a.w, 1.0f);
        float m0 = a.x * inv, m1 = a.y * inv, m2 = a.z * inv;
        float x0 = x[3 * n], x1 = x[3 * n + 1], x2 = x[3 * n + 2];
        float gA0 = 0.f, gA1 = 0.f, gB0 = 0.f, gB1 = 0.f;
#pragma unroll
        for (int k = 0; k < 32; ++k) {
            float h = m0 * sW1l[k] + m1 * sW1l[32 + k] + m2 * sW1l[64 + k]
                    + x0 * sW1r[k] + x1 * sW1r[32 + k] + x2 * sW1r[64 + k] + sb1[k];
            h = fmaxf(h, 0.0f);
            gA0 += h * sA[2 * k];     gA1 += h * sA[2 * k + 1];
            gB0 += h * sB[2 * k];     gB1 += h * sB[2 * k + 1];
        }
        *(float2*)(g1 + 2 * (size_t)n) = make_float2(gA0, gA1);
        *(float2*)(hB + 2 * (size_t)n) = make_float2(gB0, gB1);
    }
}

__global__ void edge2_kernel(const int* __restrict__ src, const int* __restrict__ dst,
                             const float* __restrict__ g1, float* __restrict__ agg2, int E) {
    int stride = gridDim.x * blockDim.x;
    for (int e = blockIdx.x * blockDim.x + threadIdx.x; e < E; e += stride) {
        int s = src[e], d = dst[e];
        float2 g = *(const float2*)(g1 + 2 * (size_t)s);
        atomicAdd(agg2 + 2 * (size_t)d + 0, g.x);
        atomicAdd(agg2 + 2 * (size_t)d + 1, g.y);
    }
}

__global__ void node2f_kernel(const float* __restrict__ agg1, const float* __restrict__ agg2,
                              const float* __restrict__ hB, const float* __restrict__ ABc,
                              float* __restrict__ out, int N) {
    float c0 = ABc[128], c1 = ABc[129];
    int stride = gridDim.x * blockDim.x;
    for (int n = blockIdx.x * blockDim.x + threadIdx.x; n < N; n += stride) {
        float inv = 1.0f / fmaxf(agg1[4 * (size_t)n + 3], 1.0f);
        float2 a = *(const float2*)(agg2 + 2 * (size_t)n);
        float2 b = *(const float2*)(hB + 2 * (size_t)n);
        *(float2*)(out + 2 * (size_t)n) = make_float2(a.x * inv + b.x + c0,
                                                      a.y * inv + b.y + c1);
    }
}

extern "C" void kernel_launch(void* const* d_in, const int* in_sizes, int n_in,
                              void* d_out, int out_size, void* d_ws, size_t ws_size,
                              hipStream_t stream) {
    const float* x    = (const float*)d_in[0];
    const int*   ei   = (const int*)d_in[1];   // [2,E] flat: src = ei[0:E], dst = ei[E:2E]
    const float* W1l  = (const float*)d_in[2];
    const float* W1r  = (const float*)d_in[3];
    const float* b1   = (const float*)d_in[4];
    const float* W2l  = (const float*)d_in[5];
    const float* W2r  = (const float*)d_in[6];
    const float* b2   = (const float*)d_in[7];
    const float* Wlin = (const float*)d_in[8];
    const float* blin = (const float*)d_in[9];
    float* out = (float*)d_out;

    const int N = in_sizes[0] / 3;
    const int E = in_sizes[1] / 2;
    const int* src = ei;
    const int* dst = ei + E;

    // Edge chunk size: per-XCD slice, multiple of 4 for int4 loads (16B aligned).
    int EC = (((E + NCHUNK - 1) / NCHUNK) + 3) & ~3;

    size_t tiled_words = (size_t)NCHUNK * N * 4   // partials1 (partials2 reuses it)
                       + 5 * (size_t)N + 130;     // g1 + hB + inv + ABc
    if (ws_size >= tiled_words * 4) {
        float* ws  = (float*)d_ws;
        float* P   = ws;                                   // partials1 / partials2
        float* g1  = ws + (size_t)NCHUNK * N * 4;
        float* hB  = g1 + 2 * (size_t)N;
        float* inv = hB + 2 * (size_t)N;
        float* ABc = inv + (size_t)N;

        int nt1 = (N + TILE1 - 1) / TILE1;   // 49
        int nt2 = (N + TILE2 - 1) / TILE2;   // 25
        int nb  = (N + 255) / 256;

        precomp_kernel<<<1, 128, 0, stream>>>(W2l, W2r, b2, Wlin, blin, ABc);
        tile1_kernel <<<nt1 * NCHUNK, 512, 0, stream>>>(src, dst, x, P, N, E, EC);
        node1t_kernel<<<nb, 256, 0, stream>>>(P, x, W1l, W1r, b1, ABc, g1, hB, inv, N);
        tile2_kernel <<<nt2 * NCHUNK, 512, 0, stream>>>(src, dst, g1, P, N, E, EC);
        node2t_kernel<<<nb, 256, 0, stream>>>(P, inv, hB, ABc, out, N);
    } else {
        // ---- fallback: round-3 atomic-scatter path ----
        float* ws   = (float*)d_ws;
        float* agg1 = ws;                    // 4N (x0,x1,x2,count)
        float* agg2 = ws + (size_t)4 * N;    // 2N
        float* g1   = ws + (size_t)6 * N;    // 2N
        float* hB   = ws + (size_t)8 * N;    // 2N
        float* ABc  = ws + (size_t)10 * N;   // 130

        int eblocks = (E + 255) / 256;
        if (eblocks > 6144) eblocks = 6144;
        int nblocks = (N + 255) / 256;

        hipMemsetAsync(agg1, 0, (size_t)6 * N * sizeof(float), stream);
        precomp_kernel<<<1, 128, 0, stream>>>(W2l, W2r, b2, Wlin, blin, ABc);
        edge1_kernel<<<eblocks, 256, 0, stream>>>(src, dst, x, agg1, E);
        node1f_kernel<<<nblocks, 256, 0, stream>>>(agg1, x, W1l, W1r, b1, ABc, g1, hB, N);
        edge2_kernel<<<eblocks, 256, 0, stream>>>(src, dst, g1, agg2, E);
        node2f_kernel<<<nblocks, 256, 0, stream>>>(agg1, agg2, hB, ABc, out, N);
    }
}

// Round 7
// 459.304 us; speedup vs baseline: 4.4135x; 2.0509x over previous
//
#include <hip/hip_runtime.h>

// GraphSAGE 2-layer + linear head, N=200000, E=6.4M.
//
// out = mean2 @ (W2l@Wlin) + h1 @ (W2r@Wlin) + (b2@Wlin + blin)
//   A = W2l@Wlin (32x2), B = W2r@Wlin (32x2), c = b2@Wlin + blin (2)
//
// Round-6: round-5's tile kernels were latency-concurrency-bound (~5 B/cyc/CU:
// 1 outstanding 16B load/thread, 392-block grid imbalanced on 512 slots).
// Fix: (a) batch 4 independent int4 loads per thread per iteration (dst+src,
// 8 edges, 64B in flight/thread), (b) exactly-balanced 512-block grids
// (64 tiles x 8 chunks / 32 tiles x 16 chunks), (c) src pre-streamed so the
// hit block has no dependent load chain. ws layout/size identical to round 5.
//
// ws layout (floats):
//   [0 .. 32N)    partials1 (8 chunks x N x float4) / partials2 (16 x N x float2)
//   [32N .. +2N)  g1
//   [.. +2N)      hB
//   [.. +N)       inv
//   [.. +130)     ABc
// Fallback (ws too small): round-3 atomic-scatter path.

#define NCHUNK1 8
#define NCHUNK2 16
#define TILE1 3136          // 64 tiles * 3136 = 200704 >= N ; LDS 3136*16B = 49KB
#define NTILE1 64
#define TILE2 6272          // 32 tiles * 6272 = 200704 >= N ; LDS 6272*8B = 49KB
#define NTILE2 32

// ---------- fold layer-2 + head ----------
__global__ void precomp_kernel(const float* __restrict__ W2l, const float* __restrict__ W2r,
                               const float* __restrict__ b2, const float* __restrict__ Wlin,
                               const float* __restrict__ blin, float* __restrict__ ABc) {
    int t = threadIdx.x;
    if (t < 64) {
        int r = t >> 1, c = t & 1;
        float sA = 0.f, sB = 0.f;
        for (int k = 0; k < 16; ++k) {
            float w = Wlin[k * 2 + c];
            sA += W2l[r * 16 + k] * w;   // W2l is (32,16) row-major
            sB += W2r[r * 16 + k] * w;
        }
        ABc[t] = sA;
        ABc[64 + t] = sB;
    } else if (t < 66) {
        int c = t - 64;
        float s = blin[c];
        for (int k = 0; k < 16; ++k) s += b2[k] * Wlin[k * 2 + c];
        ABc[128 + c] = s;
    }
}

// ---------- layer-1 tiled scatter: acc[dst-base] += (x[src],1) in LDS ----------
__global__ __launch_bounds__(512) void tile1_kernel(const int* __restrict__ src,
        const int* __restrict__ dst, const float* __restrict__ x,
        float* __restrict__ partials1, int N, int E, int EC) {
    __shared__ float acc[TILE1 * 4];
    const int tid = threadIdx.x;
    const int chunk = blockIdx.x & (NCHUNK1 - 1);   // == XCD id under round-robin
    const int base = (blockIdx.x >> 3) * TILE1;
    for (int i = tid; i < TILE1 * 4; i += 512) acc[i] = 0.f;
    __syncthreads();

    int e0 = chunk * EC; if (e0 > E) e0 = E;
    int e1 = e0 + EC;    if (e1 > E) e1 = E;

#define PROC1(dd, ss) { unsigned r = (unsigned)(dd) - (unsigned)base;            \
    if (r < (unsigned)TILE1) { const float* xp = x + 3 * (size_t)(unsigned)(ss); \
        atomicAdd(&acc[r * 4 + 0], xp[0]); atomicAdd(&acc[r * 4 + 1], xp[1]);    \
        atomicAdd(&acc[r * 4 + 2], xp[2]); atomicAdd(&acc[r * 4 + 3], 1.0f); } }

    // batched main loop: 8 edges / thread / iter, 4 independent 16B loads
    for (int p = e0 + tid * 8; p + 7 < e1; p += 512 * 8) {
        int4 d0 = *(const int4*)(dst + p);
        int4 d1 = *(const int4*)(dst + p + 4);
        int4 s0 = *(const int4*)(src + p);
        int4 s1 = *(const int4*)(src + p + 4);
        PROC1(d0.x, s0.x); PROC1(d0.y, s0.y); PROC1(d0.z, s0.z); PROC1(d0.w, s0.w);
        PROC1(d1.x, s1.x); PROC1(d1.y, s1.y); PROC1(d1.z, s1.z); PROC1(d1.w, s1.w);
    }
    // scalar tail
    int t0 = e1 - ((e1 - e0) & 7);
    for (int e = t0 + tid; e < e1; e += 512) PROC1(dst[e], src[e]);
#undef PROC1

    __syncthreads();
    float* p = partials1 + ((size_t)chunk * N + base) * 4;
    int lim = N - base; if (lim > TILE1) lim = TILE1;
    for (int i = tid; i < lim; i += 512)
        *(float4*)(p + (size_t)i * 4) = *(const float4*)(acc + i * 4);
}

// ---------- node pass 1: sum partials -> mean1 -> h1 (regs) -> g1,hB; store inv ----------
__global__ void node1t_kernel(const float* __restrict__ partials1, const float* __restrict__ x,
                              const float* __restrict__ W1l, const float* __restrict__ W1r,
                              const float* __restrict__ b1, const float* __restrict__ ABc,
                              float* __restrict__ g1, float* __restrict__ hB,
                              float* __restrict__ invArr, int N) {
    __shared__ float sW1l[96], sW1r[96], sb1[32], sA[64], sB[64];
    int tid = threadIdx.x;
    for (int i = tid; i < 96; i += 256) { sW1l[i] = W1l[i]; sW1r[i] = W1r[i]; }
    for (int i = tid; i < 32; i += 256) sb1[i] = b1[i];
    for (int i = tid; i < 64; i += 256) { sA[i] = ABc[i]; sB[i] = ABc[64 + i]; }
    __syncthreads();
    int n = blockIdx.x * 256 + tid;
    if (n >= N) return;
    float sx = 0.f, sy = 0.f, sz = 0.f, cw = 0.f;
#pragma unroll
    for (int c = 0; c < NCHUNK1; ++c) {
        float4 v = *(const float4*)(partials1 + ((size_t)c * N + n) * 4);
        sx += v.x; sy += v.y; sz += v.z; cw += v.w;
    }
    float inv = 1.0f / fmaxf(cw, 1.0f);
    float m0 = sx * inv, m1 = sy * inv, m2 = sz * inv;
    float x0 = x[3 * (size_t)n], x1 = x[3 * (size_t)n + 1], x2 = x[3 * (size_t)n + 2];
    float gA0 = 0.f, gA1 = 0.f, gB0 = 0.f, gB1 = 0.f;
#pragma unroll
    for (int k = 0; k < 32; ++k) {
        float h = m0 * sW1l[k] + m1 * sW1l[32 + k] + m2 * sW1l[64 + k]
                + x0 * sW1r[k] + x1 * sW1r[32 + k] + x2 * sW1r[64 + k] + sb1[k];
        h = fmaxf(h, 0.0f);
        gA0 += h * sA[2 * k];     gA1 += h * sA[2 * k + 1];
        gB0 += h * sB[2 * k];     gB1 += h * sB[2 * k + 1];
    }
    *(float2*)(g1 + 2 * (size_t)n) = make_float2(gA0, gA1);
    *(float2*)(hB + 2 * (size_t)n) = make_float2(gB0, gB1);
    invArr[n] = inv;
}

// ---------- layer-2 tiled scatter: acc[dst-base] += g1[src] in LDS ----------
__global__ __launch_bounds__(512) void tile2_kernel(const int* __restrict__ src,
        const int* __restrict__ dst, const float* __restrict__ g1,
        float* __restrict__ partials2, int N, int E, int EC) {
    __shared__ float acc[TILE2 * 2];
    const int tid = threadIdx.x;
    const int chunk = blockIdx.x & (NCHUNK2 - 1);
    const int base = (blockIdx.x >> 4) * TILE2;
    for (int i = tid; i < TILE2 * 2; i += 512) acc[i] = 0.f;
    __syncthreads();

    int e0 = chunk * EC; if (e0 > E) e0 = E;
    int e1 = e0 + EC;    if (e1 > E) e1 = E;

#define PROC2(dd, ss) { unsigned r = (unsigned)(dd) - (unsigned)base;            \
    if (r < (unsigned)TILE2) {                                                   \
        float2 g = *(const float2*)(g1 + 2 * (size_t)(unsigned)(ss));            \
        atomicAdd(&acc[r * 2 + 0], g.x); atomicAdd(&acc[r * 2 + 1], g.y); } }

    for (int p = e0 + tid * 8; p + 7 < e1; p += 512 * 8) {
        int4 d0 = *(const int4*)(dst + p);
        int4 d1 = *(const int4*)(dst + p + 4);
        int4 s0 = *(const int4*)(src + p);
        int4 s1 = *(const int4*)(src + p + 4);
        PROC2(d0.x, s0.x); PROC2(d0.y, s0.y); PROC2(d0.z, s0.z); PROC2(d0.w, s0.w);
        PROC2(d1.x, s1.x); PROC2(d1.y, s1.y); PROC2(d1.z, s1.z); PROC2(d1.w, s1.w);
    }
    int t0 = e1 - ((e1 - e0) & 7);
    for (int e = t0 + tid; e < e1; e += 512) PROC2(dst[e], src[e]);
#undef PROC2

    __syncthreads();
    float* p = partials2 + ((size_t)chunk * N + base) * 2;
    int lim = N - base; if (lim > TILE2) lim = TILE2;
    for (int i = tid; i < lim; i += 512)
        *(float2*)(p + (size_t)i * 2) = *(const float2*)(acc + i * 2);
}

// ---------- node pass 2: out = (sum partials2)*inv + hB + c ----------
__global__ void node2t_kernel(const float* __restrict__ partials2, const float* __restrict__ invArr,
                              const float* __restrict__ hB, const float* __restrict__ ABc,
                              float* __restrict__ out, int N) {
    int n = blockIdx.x * 256 + threadIdx.x;
    if (n >= N) return;
    float c0 = ABc[128], c1 = ABc[129];
    float s0 = 0.f, s1 = 0.f;
#pragma unroll
    for (int c = 0; c < NCHUNK2; ++c) {
        float2 v = *(const float2*)(partials2 + ((size_t)c * N + n) * 2);
        s0 += v.x; s1 += v.y;
    }
    float inv = invArr[n];
    float2 b = *(const float2*)(hB + 2 * (size_t)n);
    *(float2*)(out + 2 * (size_t)n) = make_float2(s0 * inv + b.x + c0,
                                                  s1 * inv + b.y + c1);
}

// ---------- fallback path (round-3, atomic scatter; proven) ----------
__global__ void edge1_kernel(const int* __restrict__ src, const int* __restrict__ dst,
                             const float* __restrict__ x, float* __restrict__ agg1, int E) {
    int stride = gridDim.x * blockDim.x;
    for (int e = blockIdx.x * blockDim.x + threadIdx.x; e < E; e += stride) {
        int s = src[e], d = dst[e];
        float* p = agg1 + 4 * (size_t)d;
        atomicAdd(p + 0, x[3 * s]);
        atomicAdd(p + 1, x[3 * s + 1]);
        atomicAdd(p + 2, x[3 * s + 2]);
        atomicAdd(p + 3, 1.0f);
    }
}

__global__ void node1f_kernel(const float* __restrict__ agg1, const float* __restrict__ x,
                              const float* __restrict__ W1l, const float* __restrict__ W1r,
                              const float* __restrict__ b1, const float* __restrict__ ABc,
                              float* __restrict__ g1, float* __restrict__ hB, int N) {
    __shared__ float sW1l[96], sW1r[96], sb1[32], sA[64], sB[64];
    int tid = threadIdx.x, bs = blockDim.x;
    for (int i = tid; i < 96; i += bs) { sW1l[i] = W1l[i]; sW1r[i] = W1r[i]; }
    for (int i = tid; i < 32; i += bs) sb1[i] = b1[i];
    for (int i = tid; i < 64; i += bs) { sA[i] = ABc[i]; sB[i] = ABc[64 + i]; }
    __syncthreads();
    int stride = gridDim.x * bs;
    for (int n = blockIdx.x * bs + tid; n < N; n += stride) {
        float4 a = *(const float4*)(agg1 + 4 * (size_t)n);
        float inv = 1.0f / fmaxf(a.w, 1.0f);
        float m0 = a.x * inv, m1 = a.y * inv, m2 = a.z * inv;
        float x0 = x[3 * n], x1 = x[3 * n + 1], x2 = x[3 * n + 2];
        float gA0 = 0.f, gA1 = 0.f, gB0 = 0.f, gB1 = 0.f;
#pragma unroll
        for (int k = 0; k < 32; ++k) {
            float h = m0 * sW1l[k] + m1 * sW1l[32 + k] + m2 * sW1l[64 + k]
                    + x0 * sW1r[k] + x1 * sW1r[32 + k] + x2 * sW1r[64 + k] + sb1[k];
            h = fmaxf(h, 0.0f);
            gA0 += h * sA[2 * k];     gA1 += h * sA[2 * k + 1];
            gB0 += h * sB[2 * k];     gB1 += h * sB[2 * k + 1];
        }
        *(float2*)(g1 + 2 * (size_t)n) = make_float2(gA0, gA1);
        *(float2*)(hB + 2 * (size_t)n) = make_float2(gB0, gB1);
    }
}

__global__ void edge2_kernel(const int* __restrict__ src, const int* __restrict__ dst,
                             const float* __restrict__ g1, float* __restrict__ agg2, int E) {
    int stride = gridDim.x * blockDim.x;
    for (int e = blockIdx.x * blockDim.x + threadIdx.x; e < E; e += stride) {
        int s = src[e], d = dst[e];
        float2 g = *(const float2*)(g1 + 2 * (size_t)s);
        atomicAdd(agg2 + 2 * (size_t)d + 0, g.x);
        atomicAdd(agg2 + 2 * (size_t)d + 1, g.y);
    }
}

__global__ void node2f_kernel(const float* __restrict__ agg1, const float* __restrict__ agg2,
                              const float* __restrict__ hB, const float* __restrict__ ABc,
                              float* __restrict__ out, int N) {
    float c0 = ABc[128], c1 = ABc[129];
    int stride = gridDim.x * blockDim.x;
    for (int n = blockIdx.x * blockDim.x + threadIdx.x; n < N; n += stride) {
        float inv = 1.0f / fmaxf(agg1[4 * (size_t)n + 3], 1.0f);
        float2 a = *(const float2*)(agg2 + 2 * (size_t)n);
        float2 b = *(const float2*)(hB + 2 * (size_t)n);
        *(float2*)(out + 2 * (size_t)n) = make_float2(a.x * inv + b.x + c0,
                                                      a.y * inv + b.y + c1);
    }
}

extern "C" void kernel_launch(void* const* d_in, const int* in_sizes, int n_in,
                              void* d_out, int out_size, void* d_ws, size_t ws_size,
                              hipStream_t stream) {
    const float* x    = (const float*)d_in[0];
    const int*   ei   = (const int*)d_in[1];   // [2,E] flat: src = ei[0:E], dst = ei[E:2E]
    const float* W1l  = (const float*)d_in[2];
    const float* W1r  = (const float*)d_in[3];
    const float* b1   = (const float*)d_in[4];
    const float* W2l  = (const float*)d_in[5];
    const float* W2r  = (const float*)d_in[6];
    const float* b2   = (const float*)d_in[7];
    const float* Wlin = (const float*)d_in[8];
    const float* blin = (const float*)d_in[9];
    float* out = (float*)d_out;

    const int N = in_sizes[0] / 3;
    const int E = in_sizes[1] / 2;
    const int* src = ei;
    const int* dst = ei + E;

    // Per-chunk edge slices, multiples of 16 for batched int4 loads.
    int EC1 = (((E + NCHUNK1 - 1) / NCHUNK1) + 15) & ~15;
    int EC2 = (((E + NCHUNK2 - 1) / NCHUNK2) + 15) & ~15;

    // partials region: max(8*N*4, 16*N*2) = 32N floats (identical both layers)
    size_t tiled_words = 32 * (size_t)N + 5 * (size_t)N + 130;
    if (ws_size >= tiled_words * 4 && N <= NTILE1 * TILE1 && N <= NTILE2 * TILE2) {
        float* ws  = (float*)d_ws;
        float* P   = ws;                          // partials1 / partials2 (reused)
        float* g1  = ws + 32 * (size_t)N;
        float* hB  = g1 + 2 * (size_t)N;
        float* inv = hB + 2 * (size_t)N;
        float* ABc = inv + (size_t)N;

        int nb = (N + 255) / 256;

        precomp_kernel<<<1, 128, 0, stream>>>(W2l, W2r, b2, Wlin, blin, ABc);
        tile1_kernel <<<NTILE1 * NCHUNK1, 512, 0, stream>>>(src, dst, x, P, N, E, EC1);
        node1t_kernel<<<nb, 256, 0, stream>>>(P, x, W1l, W1r, b1, ABc, g1, hB, inv, N);
        tile2_kernel <<<NTILE2 * NCHUNK2, 512, 0, stream>>>(src, dst, g1, P, N, E, EC2);
        node2t_kernel<<<nb, 256, 0, stream>>>(P, inv, hB, ABc, out, N);
    } else {
        // ---- fallback: round-3 atomic-scatter path ----
        float* ws   = (float*)d_ws;
        float* agg1 = ws;                    // 4N (x0,x1,x2,count)
        float* agg2 = ws + (size_t)4 * N;    // 2N
        float* g1   = ws + (size_t)6 * N;    // 2N
        float* hB   = ws + (size_t)8 * N;    // 2N
        float* ABc  = ws + (size_t)10 * N;   // 130

        int eblocks = (E + 255) / 256;
        if (eblocks > 6144) eblocks = 6144;
        int nblocks = (N + 255) / 256;

        hipMemsetAsync(agg1, 0, (size_t)6 * N * sizeof(float), stream);
        precomp_kernel<<<1, 128, 0, stream>>>(W2l, W2r, b2, Wlin, blin, ABc);
        edge1_kernel<<<eblocks, 256, 0, stream>>>(src, dst, x, agg1, E);
        node1f_kernel<<<nblocks, 256, 0, stream>>>(agg1, x, W1l, W1r, b1, ABc, g1, hB, N);
        edge2_kernel<<<eblocks, 256, 0, stream>>>(src, dst, g1, agg2, E);
        node2f_kernel<<<nblocks, 256, 0, stream>>>(agg1, agg2, hB, ABc, out, N);
    }
}